// Round 4
// baseline (216.302 us; speedup 1.0000x reference)
//
#include <hip/hip_runtime.h>
#include <hip/hip_fp16.h>
#include <hip/hip_fp8.h>
#include <math.h>

#define DIM 128
#define NBMAX 8   // max buckets (src >> shift), shift chosen so NB <= 8

typedef _Float16 half8 __attribute__((ext_vector_type(8)));
typedef _Float16 half2v __attribute__((ext_vector_type(2)));
typedef float floatx4 __attribute__((ext_vector_type(4)));
typedef int intx4 __attribute__((ext_vector_type(4)));

// Storage column permutation: sigma(c) = (c&15)*8 + (c>>4), applied identically
// to H, R', T, W2 -> dot invariant. Lane l of a 16-lane group owns permuted
// positions l*8..l*8+7 == orig cols {i*16+l}. Verified in R5-R7 runs.

// ---------------------------------------------------------------------------
// MFMA precompute (single dispatch, 128 rows/block, 256 thr = 4 waves):
//   blocks [0,nHB)        : H  = h          @ W1[  0:128]            -> fp8 e4m3
//   blocks [nHB,+nRB)     : R' = rel_table  @ W1[128:256] + c0       -> fp16
//   blocks [nHB+nRB,...)  : T  = time_table @ W1[384:512]            -> fp16
// Block 0 additionally zeroes the bucket histogram (stream-ordered before P1).
// ---------------------------------------------------------------------------
__global__ __launch_bounds__(256) void precompute(
    const float* __restrict__ h, const float* __restrict__ rel,
    const float* __restrict__ tim, const int* __restrict__ qrel,
    const float* __restrict__ W1, const float* __restrict__ b1,
    unsigned char* __restrict__ H8, __half* __restrict__ Rh, __half* __restrict__ Th,
    int n_nodes, int n_rels, int n_times, int nHB, int nRB,
    int* __restrict__ hist)
{
    const int tid = threadIdx.x;
    const int b = blockIdx.x;

    if (hist && b == 0 && tid < NBMAX) hist[tid] = 0;

    const float* A; int M, k0, row0; bool isR = false, isH = false;
    __half* Out = nullptr;
    if (b < nHB)            { A = h;   isH = true; M = n_nodes; k0 = 0;   row0 = b * 128; }
    else if (b < nHB + nRB) { A = rel; Out = Rh;   M = n_rels;  k0 = 128; row0 = (b - nHB) * 128; isR = true; }
    else                    { A = tim; Out = Th;   M = n_times; k0 = 384; row0 = (b - nHB - nRB) * 128; }

    __shared__ _Float16 fragB[32 * 64 * 8];  // 32 KB: [ct*4+kc][lane][j]
    __shared__ float c0f[DIM];

#pragma unroll
    for (int it = 0; it < 8; ++it) {
        const int o = tid + it * 256;
        const int ctkc = o >> 6, L = o & 63;
        const int ct = ctkc >> 2, kc = ctkc & 3;
        const int q = L >> 4, n15 = L & 15;
        const float* base = W1 + (size_t)(k0 + kc * 32 + q * 8) * DIM + ct * 16 + n15;
        half8 f;
#pragma unroll
        for (int j = 0; j < 8; ++j) f[j] = (_Float16)base[(size_t)j * DIM];
        *(half8*)&fragB[o * 8] = f;
    }
    if (isR && tid < DIM) {  // c0[n] = b1[n] + rel[q] @ W1[256:384]  (orig cols)
        const int q = qrel[0];
        const float* hq = rel + (size_t)q * DIM;
        float s = b1[tid];
        for (int k = 0; k < DIM; ++k)
            s = fmaf(hq[k], W1[(size_t)(256 + k) * DIM + tid], s);
        c0f[tid] = s;
    }
    __syncthreads();

    const int w = tid >> 6;          // wave 0..3 -> rows [row0+w*32, +32)
    const int lane = tid & 63;
    const int m15 = lane & 15, q = lane >> 4;

    const float* aBase[2];
#pragma unroll
    for (int mt = 0; mt < 2; ++mt) {
        int arow = row0 + w * 32 + mt * 16 + m15;
        if (arow >= M) arow = M - 1;     // clamp (stores guarded below)
        aBase[mt] = A + (size_t)arow * DIM + q * 8;
    }

    floatx4 acc[2][8];
#pragma unroll
    for (int mt = 0; mt < 2; ++mt)
#pragma unroll
        for (int ct = 0; ct < 8; ++ct) acc[mt][ct] = (floatx4)0.f;

#pragma unroll
    for (int kc = 0; kc < 4; ++kc) {
        half8 af[2];
#pragma unroll
        for (int mt = 0; mt < 2; ++mt) {
            const float4 a0 = *(const float4*)(aBase[mt] + kc * 32);
            const float4 a1 = *(const float4*)(aBase[mt] + kc * 32 + 4);
            af[mt][0] = (_Float16)a0.x; af[mt][1] = (_Float16)a0.y;
            af[mt][2] = (_Float16)a0.z; af[mt][3] = (_Float16)a0.w;
            af[mt][4] = (_Float16)a1.x; af[mt][5] = (_Float16)a1.y;
            af[mt][6] = (_Float16)a1.z; af[mt][7] = (_Float16)a1.w;
        }
#pragma unroll
        for (int ct = 0; ct < 8; ++ct) {
            const half8 bf = *(half8*)&fragB[(((ct * 4 + kc) * 64) + lane) * 8];
            acc[0][ct] = __builtin_amdgcn_mfma_f32_16x16x32_f16(af[0], bf, acc[0][ct], 0, 0, 0);
            acc[1][ct] = __builtin_amdgcn_mfma_f32_16x16x32_f16(af[1], bf, acc[1][ct], 0, 0, 0);
        }
    }

    float cadd[8];
#pragma unroll
    for (int ct = 0; ct < 8; ++ct) cadd[ct] = isR ? c0f[ct * 16 + m15] : 0.f;

    // Permuted epilogue. C/D layout: col = lane&15, row = (lane>>4)*4 + reg.
#pragma unroll
    for (int mt = 0; mt < 2; ++mt)
#pragma unroll
        for (int r = 0; r < 4; ++r) {
            const int m = row0 + w * 32 + mt * 16 + q * 4 + r;
            if (m < M) {
                if (isH) {
                    uint2 pk;
#if __has_builtin(__builtin_amdgcn_cvt_pk_fp8_f32)
                    int w0 = 0, w1 = 0;
                    w0 = __builtin_amdgcn_cvt_pk_fp8_f32(acc[mt][0][r], acc[mt][1][r], w0, false);
                    w0 = __builtin_amdgcn_cvt_pk_fp8_f32(acc[mt][2][r], acc[mt][3][r], w0, true);
                    w1 = __builtin_amdgcn_cvt_pk_fp8_f32(acc[mt][4][r], acc[mt][5][r], w1, false);
                    w1 = __builtin_amdgcn_cvt_pk_fp8_f32(acc[mt][6][r], acc[mt][7][r], w1, true);
                    pk.x = (unsigned)w0; pk.y = (unsigned)w1;
#else
                    union { uint2 u; unsigned char bb[8]; } pu;
#pragma unroll
                    for (int ct = 0; ct < 8; ++ct)
                        pu.bb[ct] = __hip_fp8_e4m3(acc[mt][ct][r]).__x;
                    pk = pu.u;
#endif
                    *(uint2*)(H8 + (size_t)m * DIM + m15 * 8) = pk;    // b64, coalesced
                } else {
                    half8 hv;
#pragma unroll
                    for (int ct = 0; ct < 8; ++ct)
                        hv[ct] = (_Float16)(acc[mt][ct][r] + cadd[ct]);
                    *(half8*)(Out + (size_t)m * DIM + m15 * 8) = hv;   // b128, coalesced
                }
            }
        }
}

// ---------------------------------------------------------------------------
// Bucketing preprocessing (R11):
//   P1 hist: per-block LDS histogram of src>>shift, global atomicAdd.
//   P2 scan: 1 thread, exclusive prefix over <=8 buckets -> base[], cursor[].
//   P3 scatter: per-block batches of 4096 edges; LDS count -> one global
//      atomicAdd reservation per bucket per batch -> scatter packed
//      (src,type,time,orig) int4 records. Order within bucket arbitrary
//      (valid: per-edge math is order-independent; results keyed by orig).
// ---------------------------------------------------------------------------
__global__ __launch_bounds__(256) void hist_kernel(
    const int* __restrict__ ei, int E, int shift, int* __restrict__ hist)
{
    __shared__ int lh[NBMAX];
    if (threadIdx.x < NBMAX) lh[threadIdx.x] = 0;
    __syncthreads();
    for (int e = blockIdx.x * 256 + threadIdx.x; e < E; e += gridDim.x * 256)
        atomicAdd(&lh[(unsigned)ei[e] >> shift], 1);
    __syncthreads();
    if (threadIdx.x < NBMAX) atomicAdd(&hist[threadIdx.x], lh[threadIdx.x]);
}

__global__ void scan_kernel(const int* __restrict__ hist, int* __restrict__ base,
                            int* __restrict__ cursor, int NB)
{
    if (threadIdx.x == 0 && blockIdx.x == 0) {
        int acc = 0;
        for (int i = 0; i < NB; ++i) { base[i] = acc; cursor[i] = acc; acc += hist[i]; }
        base[NB] = acc;
    }
}

#define SC_CH 4096
__global__ __launch_bounds__(256) void scatter_kernel(
    const int* __restrict__ ei, const int* __restrict__ ety,
    const int* __restrict__ eti, int E, int shift,
    int* __restrict__ cursor, intx4* __restrict__ perm)
{
    __shared__ int lh[NBMAX], lbase[NBMAX], lpos[NBMAX];
    const int nBatch = (E + SC_CH - 1) / SC_CH;
    for (int batch = blockIdx.x; batch < nBatch; batch += gridDim.x) {
        const int e0 = batch * SC_CH, e1 = min(e0 + SC_CH, E);
        if (threadIdx.x < NBMAX) lh[threadIdx.x] = 0;
        __syncthreads();
        for (int e = e0 + threadIdx.x; e < e1; e += 256)
            atomicAdd(&lh[(unsigned)ei[e] >> shift], 1);
        __syncthreads();
        if (threadIdx.x < NBMAX) {
            lbase[threadIdx.x] = atomicAdd(&cursor[threadIdx.x], lh[threadIdx.x]);
            lpos[threadIdx.x] = 0;
        }
        __syncthreads();
        for (int e = e0 + threadIdx.x; e < e1; e += 256) {
            const int s = ei[e];
            const int bk = (unsigned)s >> shift;
            const int p = lbase[bk] + atomicAdd(&lpos[bk], 1);
            intx4 rec; rec[0] = s; rec[1] = ety[e]; rec[2] = eti[e]; rec[3] = e;
            __builtin_nontemporal_store(rec, &perm[p]);
        }
        __syncthreads();
    }
}

// ---------------------------------------------------------------------------
// Edge kernels. Shared math: 16-lane groups, permuted tables, DPP reduce.
// out[e] = sigmoid(dot(relu(H[src]+R'[type]+T[time]), W2) + b2)
// ---------------------------------------------------------------------------
__device__ __forceinline__ half2v fp8x2_to_h2(unsigned u16) {
#if __has_builtin(__builtin_amdgcn_cvt_pk_f16_fp8)
    auto c = __builtin_amdgcn_cvt_pk_f16_fp8((short)u16);
    half2v r; r[0] = c[0]; r[1] = c[1];
    return r;
#else
    auto f = __builtin_amdgcn_cvt_pk_f32_fp8((int)u16, false);
    half2v r; r[0] = (_Float16)f[0]; r[1] = (_Float16)f[1];
    return r;
#endif
}

__device__ __forceinline__ float edot(uint2 hu, uint4 ru, uint4 tu,
                                      const half2v* __restrict__ w2h) {
    union U { uint4 u; half2v h[4]; };
    U R, T; R.u = ru; T.u = tu;
    const half2v z = (half2v)(_Float16)0.f;
    const unsigned hw[4] = {hu.x & 0xffffu, hu.x >> 16, hu.y & 0xffffu, hu.y >> 16};
    float p = 0.f;
#pragma unroll
    for (int j = 0; j < 4; ++j) {
        const half2v hh = fp8x2_to_h2(hw[j]);
        half2v s = hh + R.h[j] + T.h[j];                  // v_pk_add_f16 x2
        s = __builtin_elementwise_max(s, z);              // v_pk_max_f16
#if __has_builtin(__builtin_amdgcn_fdot2)
        p = __builtin_amdgcn_fdot2(s, w2h[j], p, false);  // v_dot2_f32_f16
#else
        p = fmaf((float)s[0], (float)w2h[j][0], p);
        p = fmaf((float)s[1], (float)w2h[j][1], p);
#endif
    }
    return p;
}

// DPP row_shr accumulate: after 1,2,4,8 the full 16-lane row sum is in lane 15.
template<int CTRL>
__device__ __forceinline__ float dpp_row_add(float x) {
    int s = __builtin_amdgcn_update_dpp(0, __float_as_int(x), CTRL, 0xf, 0xf, true);
    return x + __int_as_float(s);
}

// Bucketed edge kernel: all blocks sweep buckets 0..NB-1 in unison; each
// bucket's 2-MB H-slice (+T 0.5 MB +R' 0.25 MB) is L2-resident per XCD ->
// H gathers hit L2 instead of serializing on the per-CU L2-miss slots.
__global__ __launch_bounds__(256) void edge_kernel_b(
    const intx4* __restrict__ perm, const int* __restrict__ base, int NB,
    const unsigned char* __restrict__ H8, const __half* __restrict__ Rh,
    const __half* __restrict__ Th,
    const float* __restrict__ W2, const float* __restrict__ b2,
    float* __restrict__ out, int nGrpTotal)
{
    const int tid = threadIdx.x;
    const int l = tid & 15;
    const int grp = blockIdx.x * 16 + (tid >> 4);

    half2v w2h[4];
#pragma unroll
    for (int j = 0; j < 4; ++j) {
        w2h[j][0] = (_Float16)W2[(2 * j) * 16 + l];
        w2h[j][1] = (_Float16)W2[(2 * j + 1) * 16 + l];
    }
    const float b2v = b2[0];
    const unsigned char* Rh8 = (const unsigned char*)Rh;
    const unsigned char* Th8 = (const unsigned char*)Th;

    for (int k = 0; k < NB; ++k) {
        const int lo = base[k], hi = base[k + 1];
        const int nq = (hi - lo + 3) >> 2;
        for (int qd = grp; qd < nq; qd += nGrpTotal) {
            const int e0 = lo + 4 * qd;
            intx4 rec[4];
#pragma unroll
            for (int i = 0; i < 4; ++i)
                rec[i] = __builtin_nontemporal_load(&perm[min(e0 + i, hi - 1)]);

            uint2 hv[4]; uint4 rv[4], tv[4];
#pragma unroll
            for (int i = 0; i < 4; ++i) {
                hv[i] = *(const uint2*)(H8  + ((unsigned)rec[i][0] << 7) + (l << 3));
                rv[i] = *(const uint4*)(Rh8 + ((unsigned)rec[i][1] << 8) + (l << 4));
                tv[i] = *(const uint4*)(Th8 + ((unsigned)rec[i][2] << 8) + (l << 4));
            }
            float p[4];
#pragma unroll
            for (int i = 0; i < 4; ++i)
                p[i] = edot(hv[i], rv[i], tv[i], w2h);
#pragma unroll
            for (int i = 0; i < 4; ++i) {
                p[i] = dpp_row_add<0x111>(p[i]);
                p[i] = dpp_row_add<0x112>(p[i]);
                p[i] = dpp_row_add<0x114>(p[i]);
                p[i] = dpp_row_add<0x118>(p[i]);   // sum in lane 15
            }
            if (l == 15) {
#pragma unroll
                for (int i = 0; i < 4; ++i) {
                    if (e0 + i < hi) {
                        const float o = 1.f / (1.f + __expf(-(p[i] + b2v)));
                        __builtin_nontemporal_store(o, out + rec[i][3]);
                    }
                }
            }
        }
    }
}

// Direct (unbucketed) fallback = verified R9 structure.
__global__ __launch_bounds__(256) void edge_kernel_direct(
    const int* __restrict__ ei, const int* __restrict__ ety,
    const int* __restrict__ eti,
    const unsigned char* __restrict__ H8, const __half* __restrict__ Rh,
    const __half* __restrict__ Th,
    const float* __restrict__ W2, const float* __restrict__ b2,
    float* __restrict__ out, int E, int nGrpTotal)
{
    const int tid = threadIdx.x;
    const int l = tid & 15;
    int g = blockIdx.x * 16 + (tid >> 4);
    const int nQuad = (E + 3) >> 2;
    if (g >= nQuad) return;

    half2v w2h[4];
#pragma unroll
    for (int j = 0; j < 4; ++j) {
        w2h[j][0] = (_Float16)W2[(2 * j) * 16 + l];
        w2h[j][1] = (_Float16)W2[(2 * j + 1) * 16 + l];
    }
    const float b2v = b2[0];
    const bool exact = (E & 3) == 0;
    const unsigned char* Rh8 = (const unsigned char*)Rh;
    const unsigned char* Th8 = (const unsigned char*)Th;

    int s[4], r[4], t[4];
    {
        const int e0 = 4 * g;
        if (exact || e0 + 3 < E) {
#pragma unroll
            for (int i = 0; i < 4; ++i) { s[i] = ei[e0 + i]; r[i] = ety[e0 + i]; t[i] = eti[e0 + i]; }
        } else {
#pragma unroll
            for (int i = 0; i < 4; ++i) {
                const int e = min(e0 + i, E - 1);
                s[i] = ei[e]; r[i] = ety[e]; t[i] = eti[e];
            }
        }
    }

    while (true) {
        const int gn = g + nGrpTotal;
        uint2 hv[4]; uint4 rv[4], tv[4];
#pragma unroll
        for (int i = 0; i < 4; ++i) {
            hv[i] = *(const uint2*)(H8  + ((unsigned)s[i] << 7) + (l << 3));
            rv[i] = *(const uint4*)(Rh8 + ((unsigned)r[i] << 8) + (l << 4));
            tv[i] = *(const uint4*)(Th8 + ((unsigned)t[i] << 8) + (l << 4));
        }
        if (gn < nQuad) {
            const int e0 = 4 * gn;
            if (exact || e0 + 3 < E) {
#pragma unroll
                for (int i = 0; i < 4; ++i) { s[i] = ei[e0 + i]; r[i] = ety[e0 + i]; t[i] = eti[e0 + i]; }
            } else {
#pragma unroll
                for (int i = 0; i < 4; ++i) {
                    const int e = min(e0 + i, E - 1);
                    s[i] = ei[e]; r[i] = ety[e]; t[i] = eti[e];
                }
            }
        }
        float p[4];
#pragma unroll
        for (int i = 0; i < 4; ++i)
            p[i] = edot(hv[i], rv[i], tv[i], w2h);
#pragma unroll
        for (int i = 0; i < 4; ++i) {
            p[i] = dpp_row_add<0x111>(p[i]);
            p[i] = dpp_row_add<0x112>(p[i]);
            p[i] = dpp_row_add<0x114>(p[i]);
            p[i] = dpp_row_add<0x118>(p[i]);
        }
        if (l == 15) {
            const int e0 = 4 * g;
            floatx4 o;
            o[0] = 1.f / (1.f + __expf(-(p[0] + b2v)));
            o[1] = 1.f / (1.f + __expf(-(p[1] + b2v)));
            o[2] = 1.f / (1.f + __expf(-(p[2] + b2v)));
            o[3] = 1.f / (1.f + __expf(-(p[3] + b2v)));
            if (e0 + 3 < E) {
                *(floatx4*)(out + e0) = o;
            } else {
                const float ov[4] = {o[0], o[1], o[2], o[3]};
                for (int i = 0; i < 4 && e0 + i < E; ++i) out[e0 + i] = ov[i];
            }
        }
        if (gn >= nQuad) break;
        g = gn;
    }
}

extern "C" void kernel_launch(void* const* d_in, const int* in_sizes, int n_in,
                              void* d_out, int out_size, void* d_ws, size_t ws_size,
                              hipStream_t stream) {
    const float* h          = (const float*)d_in[0];
    const int*   edge_index = (const int*)d_in[1];   // [2,E] flat; row 0 = src
    const int*   edge_type  = (const int*)d_in[2];
    const int*   edge_time  = (const int*)d_in[3];
    const int*   query_rel  = (const int*)d_in[4];
    const float* rel_table  = (const float*)d_in[5];
    const float* time_table = (const float*)d_in[6];
    const float* W1         = (const float*)d_in[7]; // [512,128] row-major
    const float* b1         = (const float*)d_in[8];
    const float* W2         = (const float*)d_in[9]; // [128,1]
    const float* b2         = (const float*)d_in[10];
    float* out = (float*)d_out;

    const int n_nodes = in_sizes[0] / DIM;
    const int E       = in_sizes[2];
    const int n_rels  = in_sizes[5] / DIM;
    const int n_times = in_sizes[6] / DIM;

    // Workspace layout
    const size_t szH = ((size_t)n_nodes * DIM + 255) & ~(size_t)255;
    const size_t szR = ((size_t)n_rels * DIM * 2 + 255) & ~(size_t)255;
    const size_t szT = ((size_t)n_times * DIM * 2 + 255) & ~(size_t)255;
    const size_t szP = (((size_t)E * 16) + 255) & ~(size_t)255;
    unsigned char* H8 = (unsigned char*)d_ws;
    __half* Rh = (__half*)(H8 + szH);
    __half* Th = (__half*)(H8 + szH + szR);
    intx4* perm = (intx4*)(H8 + szH + szR + szT);
    int* counters = (int*)(H8 + szH + szR + szT + szP);   // hist[8], cursor[8], base[9]
    const bool bucketed = (szH + szR + szT + szP + 256) <= ws_size;

    int* histP   = counters + 0;
    int* cursorP = counters + 8;
    int* baseP   = counters + 16;

    // Bucket shift: smallest shift with ((n_nodes-1)>>shift) < 8.
    int shift = 0;
    while (((unsigned)(n_nodes - 1) >> shift) >= NBMAX) ++shift;
    const int NB = (int)(((unsigned)(n_nodes - 1) >> shift) + 1);

    const int nHB = (n_nodes + 127) / 128;
    const int nRB = (n_rels + 127) / 128;
    const int nTB = (n_times + 127) / 128;

    precompute<<<nHB + nRB + nTB, 256, 0, stream>>>(
        h, rel_table, time_table, query_rel, W1, b1,
        H8, Rh, Th, n_nodes, n_rels, n_times, nHB, nRB,
        bucketed ? histP : nullptr);

    if (bucketed) {
        hist_kernel<<<256, 256, 0, stream>>>(edge_index, E, shift, histP);
        scan_kernel<<<1, 64, 0, stream>>>(histP, baseP, cursorP, NB);
        scatter_kernel<<<256, 256, 0, stream>>>(
            edge_index, edge_type, edge_time, E, shift, cursorP, perm);

        const int nBlk = 2048;   // 8 blocks/CU, 16 groups/blk
        edge_kernel_b<<<nBlk, 256, 0, stream>>>(
            perm, baseP, NB, H8, Rh, Th, W2, b2, out, nBlk * 16);
    } else {
        const int nBlk = 4096;
        edge_kernel_direct<<<nBlk, 256, 0, stream>>>(
            edge_index, edge_type, edge_time, H8, Rh, Th, W2, b2,
            out, E, nBlk * 16);
    }
}

// Round 5
// 162.147 us; speedup vs baseline: 1.3340x; 1.3340x over previous
//
#include <hip/hip_runtime.h>
#include <hip/hip_fp16.h>
#include <hip/hip_fp8.h>
#include <math.h>

#define DIM 128

typedef _Float16 half8 __attribute__((ext_vector_type(8)));
typedef _Float16 half2v __attribute__((ext_vector_type(2)));
typedef float floatx4 __attribute__((ext_vector_type(4)));

// Storage column permutation: sigma(c) = (c&15)*8 + (c>>4), applied identically
// to H, R', T, W2 -> dot invariant. Lane l of a 16-lane group owns permuted
// positions l*8..l*8+7 == orig cols {i*16+l}. Verified in R5-R7 runs.

// ---------------------------------------------------------------------------
// MFMA precompute (single dispatch, 128 rows/block, 256 thr = 4 waves):
//   blocks [0,nHB)        : H  = h          @ W1[  0:128]            -> fp8 e4m3
//   blocks [nHB,+nRB)     : R' = rel_table  @ W1[128:256] + c0       -> fp16
//   blocks [nHB+nRB,...)  : T  = time_table @ W1[384:512]            -> fp16
// (unchanged from verified R9 round)
// ---------------------------------------------------------------------------
__global__ __launch_bounds__(256) void precompute(
    const float* __restrict__ h, const float* __restrict__ rel,
    const float* __restrict__ tim, const int* __restrict__ qrel,
    const float* __restrict__ W1, const float* __restrict__ b1,
    unsigned char* __restrict__ H8, __half* __restrict__ Rh, __half* __restrict__ Th,
    int n_nodes, int n_rels, int n_times, int nHB, int nRB)
{
    const int tid = threadIdx.x;
    const int b = blockIdx.x;

    const float* A; int M, k0, row0; bool isR = false, isH = false;
    __half* Out = nullptr;
    if (b < nHB)            { A = h;   isH = true; M = n_nodes; k0 = 0;   row0 = b * 128; }
    else if (b < nHB + nRB) { A = rel; Out = Rh;   M = n_rels;  k0 = 128; row0 = (b - nHB) * 128; isR = true; }
    else                    { A = tim; Out = Th;   M = n_times; k0 = 384; row0 = (b - nHB - nRB) * 128; }

    __shared__ _Float16 fragB[32 * 64 * 8];  // 32 KB: [ct*4+kc][lane][j]
    __shared__ float c0f[DIM];

#pragma unroll
    for (int it = 0; it < 8; ++it) {
        const int o = tid + it * 256;
        const int ctkc = o >> 6, L = o & 63;
        const int ct = ctkc >> 2, kc = ctkc & 3;
        const int q = L >> 4, n15 = L & 15;
        const float* base = W1 + (size_t)(k0 + kc * 32 + q * 8) * DIM + ct * 16 + n15;
        half8 f;
#pragma unroll
        for (int j = 0; j < 8; ++j) f[j] = (_Float16)base[(size_t)j * DIM];
        *(half8*)&fragB[o * 8] = f;
    }
    if (isR && tid < DIM) {  // c0[n] = b1[n] + rel[q] @ W1[256:384]  (orig cols)
        const int q = qrel[0];
        const float* hq = rel + (size_t)q * DIM;
        float s = b1[tid];
        for (int k = 0; k < DIM; ++k)
            s = fmaf(hq[k], W1[(size_t)(256 + k) * DIM + tid], s);
        c0f[tid] = s;
    }
    __syncthreads();

    const int w = tid >> 6;          // wave 0..3 -> rows [row0+w*32, +32)
    const int lane = tid & 63;
    const int m15 = lane & 15, q = lane >> 4;

    const float* aBase[2];
#pragma unroll
    for (int mt = 0; mt < 2; ++mt) {
        int arow = row0 + w * 32 + mt * 16 + m15;
        if (arow >= M) arow = M - 1;     // clamp (stores guarded below)
        aBase[mt] = A + (size_t)arow * DIM + q * 8;
    }

    floatx4 acc[2][8];
#pragma unroll
    for (int mt = 0; mt < 2; ++mt)
#pragma unroll
        for (int ct = 0; ct < 8; ++ct) acc[mt][ct] = (floatx4)0.f;

#pragma unroll
    for (int kc = 0; kc < 4; ++kc) {
        half8 af[2];
#pragma unroll
        for (int mt = 0; mt < 2; ++mt) {
            const float4 a0 = *(const float4*)(aBase[mt] + kc * 32);
            const float4 a1 = *(const float4*)(aBase[mt] + kc * 32 + 4);
            af[mt][0] = (_Float16)a0.x; af[mt][1] = (_Float16)a0.y;
            af[mt][2] = (_Float16)a0.z; af[mt][3] = (_Float16)a0.w;
            af[mt][4] = (_Float16)a1.x; af[mt][5] = (_Float16)a1.y;
            af[mt][6] = (_Float16)a1.z; af[mt][7] = (_Float16)a1.w;
        }
#pragma unroll
        for (int ct = 0; ct < 8; ++ct) {
            const half8 bf = *(half8*)&fragB[(((ct * 4 + kc) * 64) + lane) * 8];
            acc[0][ct] = __builtin_amdgcn_mfma_f32_16x16x32_f16(af[0], bf, acc[0][ct], 0, 0, 0);
            acc[1][ct] = __builtin_amdgcn_mfma_f32_16x16x32_f16(af[1], bf, acc[1][ct], 0, 0, 0);
        }
    }

    float cadd[8];
#pragma unroll
    for (int ct = 0; ct < 8; ++ct) cadd[ct] = isR ? c0f[ct * 16 + m15] : 0.f;

    // Permuted epilogue. C/D layout: col = lane&15, row = (lane>>4)*4 + reg.
#pragma unroll
    for (int mt = 0; mt < 2; ++mt)
#pragma unroll
        for (int r = 0; r < 4; ++r) {
            const int m = row0 + w * 32 + mt * 16 + q * 4 + r;
            if (m < M) {
                if (isH) {
                    uint2 pk;
#if __has_builtin(__builtin_amdgcn_cvt_pk_fp8_f32)
                    int w0 = 0, w1 = 0;
                    w0 = __builtin_amdgcn_cvt_pk_fp8_f32(acc[mt][0][r], acc[mt][1][r], w0, false);
                    w0 = __builtin_amdgcn_cvt_pk_fp8_f32(acc[mt][2][r], acc[mt][3][r], w0, true);
                    w1 = __builtin_amdgcn_cvt_pk_fp8_f32(acc[mt][4][r], acc[mt][5][r], w1, false);
                    w1 = __builtin_amdgcn_cvt_pk_fp8_f32(acc[mt][6][r], acc[mt][7][r], w1, true);
                    pk.x = (unsigned)w0; pk.y = (unsigned)w1;
#else
                    union { uint2 u; unsigned char bb[8]; } pu;
#pragma unroll
                    for (int ct = 0; ct < 8; ++ct)
                        pu.bb[ct] = __hip_fp8_e4m3(acc[mt][ct][r]).__x;
                    pk = pu.u;
#endif
                    *(uint2*)(H8 + (size_t)m * DIM + m15 * 8) = pk;    // b64, coalesced
                } else {
                    half8 hv;
#pragma unroll
                    for (int ct = 0; ct < 8; ++ct)
                        hv[ct] = (_Float16)(acc[mt][ct][r] + cadd[ct]);
                    *(half8*)(Out + (size_t)m * DIM + m15 * 8) = hv;   // b128, coalesced
                }
            }
        }
}

// ---------------------------------------------------------------------------
// Edge kernel (R12 = R9 + L2-pollution control, single-variable probe):
//   - idx loads and main-path out stores are NONTEMPORAL (L2 no-allocate):
//     the 12-MB idx stream + 4-MB out stream have zero reuse and were
//     evicting H8 rows from L2. Everything else byte-identical to R9
//     (42.5 us, occupancy 57%, VGPR 36).
// out[e] = sigmoid(dot(relu(H[src]+R'[type]+T[time]), W2) + b2)
// ---------------------------------------------------------------------------
__device__ __forceinline__ half2v fp8x2_to_h2(unsigned u16) {
#if __has_builtin(__builtin_amdgcn_cvt_pk_f16_fp8)
    auto c = __builtin_amdgcn_cvt_pk_f16_fp8((short)u16);
    half2v r; r[0] = c[0]; r[1] = c[1];
    return r;
#else
    auto f = __builtin_amdgcn_cvt_pk_f32_fp8((int)u16, false);
    half2v r; r[0] = (_Float16)f[0]; r[1] = (_Float16)f[1];
    return r;
#endif
}

__device__ __forceinline__ float edot(uint2 hu, uint4 ru, uint4 tu,
                                      const half2v* __restrict__ w2h) {
    union U { uint4 u; half2v h[4]; };
    U R, T; R.u = ru; T.u = tu;
    const half2v z = (half2v)(_Float16)0.f;
    const unsigned hw[4] = {hu.x & 0xffffu, hu.x >> 16, hu.y & 0xffffu, hu.y >> 16};
    float p = 0.f;
#pragma unroll
    for (int j = 0; j < 4; ++j) {
        const half2v hh = fp8x2_to_h2(hw[j]);
        half2v s = hh + R.h[j] + T.h[j];                  // v_pk_add_f16 x2
        s = __builtin_elementwise_max(s, z);              // v_pk_max_f16
#if __has_builtin(__builtin_amdgcn_fdot2)
        p = __builtin_amdgcn_fdot2(s, w2h[j], p, false);  // v_dot2_f32_f16
#else
        p = fmaf((float)s[0], (float)w2h[j][0], p);
        p = fmaf((float)s[1], (float)w2h[j][1], p);
#endif
    }
    return p;
}

// DPP row_shr accumulate: after 1,2,4,8 the full 16-lane row sum is in lane 15.
template<int CTRL>
__device__ __forceinline__ float dpp_row_add(float x) {
    int s = __builtin_amdgcn_update_dpp(0, __float_as_int(x), CTRL, 0xf, 0xf, true);
    return x + __int_as_float(s);
}

__global__ __launch_bounds__(256) void edge_kernel(
    const int* __restrict__ ei, const int* __restrict__ ety,
    const int* __restrict__ eti,
    const unsigned char* __restrict__ H8, const __half* __restrict__ Rh,
    const __half* __restrict__ Th,
    const float* __restrict__ W2, const float* __restrict__ b2,
    float* __restrict__ out, int E, int nGrpTotal)
{
    const int tid = threadIdx.x;
    const int l = tid & 15;
    int g = blockIdx.x * 16 + (tid >> 4);
    const int nQuad = (E + 3) >> 2;
    if (g >= nQuad) return;

    // Permuted W2: lane l's 8 storage positions map to orig cols i*16 + l.
    half2v w2h[4];
#pragma unroll
    for (int j = 0; j < 4; ++j) {
        w2h[j][0] = (_Float16)W2[(2 * j) * 16 + l];
        w2h[j][1] = (_Float16)W2[(2 * j + 1) * 16 + l];
    }
    const float b2v = b2[0];
    const bool exact = (E & 3) == 0;
    const unsigned char* Rh8 = (const unsigned char*)Rh;
    const unsigned char* Th8 = (const unsigned char*)Th;

    int s[4], r[4], t[4];
    {
        const int e0 = 4 * g;
        if (exact || e0 + 3 < E) {
#pragma unroll
            for (int i = 0; i < 4; ++i) {
                s[i] = __builtin_nontemporal_load(ei + e0 + i);
                r[i] = __builtin_nontemporal_load(ety + e0 + i);
                t[i] = __builtin_nontemporal_load(eti + e0 + i);
            }
        } else {
#pragma unroll
            for (int i = 0; i < 4; ++i) {
                const int e = min(e0 + i, E - 1);
                s[i] = ei[e]; r[i] = ety[e]; t[i] = eti[e];
            }
        }
    }

    while (true) {
        const int gn = g + nGrpTotal;
        // 12 gathers in flight (32-bit voffset off uniform table bases)
        uint2 hv[4]; uint4 rv[4], tv[4];
#pragma unroll
        for (int i = 0; i < 4; ++i) {
            hv[i] = *(const uint2*)(H8  + ((unsigned)s[i] << 7) + (l << 3));
            rv[i] = *(const uint4*)(Rh8 + ((unsigned)r[i] << 8) + (l << 4));
            tv[i] = *(const uint4*)(Th8 + ((unsigned)t[i] << 8) + (l << 4));
        }
        if (gn < nQuad) {  // prefetch next indices while gathers land
            const int e0 = 4 * gn;
            if (exact || e0 + 3 < E) {
#pragma unroll
                for (int i = 0; i < 4; ++i) {
                    s[i] = __builtin_nontemporal_load(ei + e0 + i);
                    r[i] = __builtin_nontemporal_load(ety + e0 + i);
                    t[i] = __builtin_nontemporal_load(eti + e0 + i);
                }
            } else {
#pragma unroll
                for (int i = 0; i < 4; ++i) {
                    const int e = min(e0 + i, E - 1);
                    s[i] = ei[e]; r[i] = ety[e]; t[i] = eti[e];
                }
            }
        }
        float p[4];
#pragma unroll
        for (int i = 0; i < 4; ++i)
            p[i] = edot(hv[i], rv[i], tv[i], w2h);
#pragma unroll
        for (int i = 0; i < 4; ++i) {
            p[i] = dpp_row_add<0x111>(p[i]);   // row_shr:1
            p[i] = dpp_row_add<0x112>(p[i]);   // row_shr:2
            p[i] = dpp_row_add<0x114>(p[i]);   // row_shr:4
            p[i] = dpp_row_add<0x118>(p[i]);   // row_shr:8  -> sum in lane 15
        }
        if (l == 15) {
            const int e0 = 4 * g;
            floatx4 o;
            o[0] = 1.f / (1.f + __expf(-(p[0] + b2v)));
            o[1] = 1.f / (1.f + __expf(-(p[1] + b2v)));
            o[2] = 1.f / (1.f + __expf(-(p[2] + b2v)));
            o[3] = 1.f / (1.f + __expf(-(p[3] + b2v)));
            if (e0 + 3 < E) {
                __builtin_nontemporal_store(o, (floatx4*)(out + e0));
            } else {
                const float ov[4] = {o[0], o[1], o[2], o[3]};
                for (int i = 0; i < 4 && e0 + i < E; ++i) out[e0 + i] = ov[i];
            }
        }
        if (gn >= nQuad) break;
        g = gn;
    }
}

extern "C" void kernel_launch(void* const* d_in, const int* in_sizes, int n_in,
                              void* d_out, int out_size, void* d_ws, size_t ws_size,
                              hipStream_t stream) {
    const float* h          = (const float*)d_in[0];
    const int*   edge_index = (const int*)d_in[1];   // [2,E] flat; row 0 = src
    const int*   edge_type  = (const int*)d_in[2];
    const int*   edge_time  = (const int*)d_in[3];
    const int*   query_rel  = (const int*)d_in[4];
    const float* rel_table  = (const float*)d_in[5];
    const float* time_table = (const float*)d_in[6];
    const float* W1         = (const float*)d_in[7]; // [512,128] row-major
    const float* b1         = (const float*)d_in[8];
    const float* W2         = (const float*)d_in[9]; // [128,1]
    const float* b2         = (const float*)d_in[10];
    float* out = (float*)d_out;

    const int n_nodes = in_sizes[0] / DIM;
    const int E       = in_sizes[2];
    const int n_rels  = in_sizes[5] / DIM;
    const int n_times = in_sizes[6] / DIM;

    unsigned char* H8 = (unsigned char*)d_ws;                    // n_nodes*128 B
    __half* Rh = (__half*)(H8 + (((size_t)n_nodes * DIM + 255) & ~(size_t)255));
    __half* Th = Rh + (size_t)n_rels * DIM;

    const int nHB = (n_nodes + 127) / 128;
    const int nRB = (n_rels + 127) / 128;
    const int nTB = (n_times + 127) / 128;

    precompute<<<nHB + nRB + nTB, 256, 0, stream>>>(
        h, rel_table, time_table, query_rel, W1, b1,
        H8, Rh, Th, n_nodes, n_rels, n_times, nHB, nRB);

    const int nBlk = 4096;  // 2x oversubscription, grid-stride
    edge_kernel<<<nBlk, 256, 0, stream>>>(
        edge_index, edge_type, edge_time, H8, Rh, Th, W2, b2,
        out, E, nBlk * 16);
}